// Round 1
// baseline (258.185 us; speedup 1.0000x reference)
//
#include <hip/hip_runtime.h>

// NetAndTexture: fused feature-gather + barycentric blend + SH2 eval.
// out layout (floats): [HW*16 fg feats][HW*16 bg feats][HW fg mask][HW bg mask]

constexpr float SH_C0 = 0.28209479177387814f;
constexpr float SH_C1 = 0.4886025119029199f;
constexpr float C20 =  1.0925484305920792f;
constexpr float C21 = -1.0925484305920792f;
constexpr float C22 =  0.31539156525252005f;
constexpr float C23 = -1.0925484305920792f;
constexpr float C24 =  0.5462742152960396f;
constexpr float INV_R2 = 1.0f / (0.006f * 0.006f);

__global__ __launch_bounds__(256) void net_tex_kernel(
    const float* __restrict__ features,
    const float* __restrict__ dists,
    const float* __restrict__ bary,
    const float* __restrict__ rd,
    const int*  __restrict__ faces,
    const int*  __restrict__ f1idx,
    const int*  __restrict__ p2f,
    float* __restrict__ out,
    int HW, int N)
{
    int p = blockIdx.x * blockDim.x + threadIdx.x;
    if (p >= N) return;
    int s  = (p >= HW) ? 1 : 0;
    int hw = p - s * HW;

    // dirs = flip(ray_dirs over H,W) -> rd[k*HW + (HW-1-hw)]
    float x = rd[HW   - 1 - hw];
    float y = rd[2*HW - 1 - hw];
    float z = rd[3*HW - 1 - hw];
    float xx = x*x, yy = y*y, zz = z*z;
    float c[9];
    c[0] = SH_C0;
    c[1] = -SH_C1 * y;
    c[2] =  SH_C1 * z;
    c[3] = -SH_C1 * x;
    c[4] = C20 * x * y;
    c[5] = C21 * y * z;
    c[6] = C22 * (2.0f*zz - xx - yy);
    c[7] = C23 * x * z;
    c[8] = C24 * (xx - yy);

    int i1 = f1idx[p];
    int f2 = p2f[p];
    bool m1 = i1 >= 0;
    bool m2 = f2 >= 0;

    float acc[16];
    #pragma unroll
    for (int j = 0; j < 16; j++) acc[j] = 0.0f;

    if (m1) {
        float wgt = 1.0f - dists[p] * INV_R2;
        const float4* r = (const float4*)(features + (size_t)i1 * 72);
        #pragma unroll
        for (int ch = 0; ch < 18; ch++) {
            float4 v = r[ch];
            const int e = ch * 4;
            acc[(e+0)/9] += c[(e+0)%9] * v.x;
            acc[(e+1)/9] += c[(e+1)%9] * v.y;
            acc[(e+2)/9] += c[(e+2)%9] * v.z;
            acc[(e+3)/9] += c[(e+3)%9] * v.w;
        }
        #pragma unroll
        for (int j = 0; j < 8; j++) acc[j] *= wgt;
    }

    if (m2) {
        int fb = f2 * 3;
        int t0 = faces[fb+0], t1 = faces[fb+1], t2 = faces[fb+2];
        float b0 = bary[(size_t)p*3+0];
        float b1 = bary[(size_t)p*3+1];
        float b2 = bary[(size_t)p*3+2];
        const float4* r0 = (const float4*)(features + (size_t)t0 * 72);
        const float4* r1 = (const float4*)(features + (size_t)t1 * 72);
        const float4* r2 = (const float4*)(features + (size_t)t2 * 72);
        #pragma unroll
        for (int ch = 0; ch < 18; ch++) {
            float4 v0 = r0[ch], v1 = r1[ch], v2 = r2[ch];
            const int e = ch * 4;
            float f0 = b0*v0.x + b1*v1.x + b2*v2.x;
            float f1 = b0*v0.y + b1*v1.y + b2*v2.y;
            float g2 = b0*v0.z + b1*v1.z + b2*v2.z;
            float f3 = b0*v0.w + b1*v1.w + b2*v2.w;
            acc[8+(e+0)/9] += c[(e+0)%9] * f0;
            acc[8+(e+1)/9] += c[(e+1)%9] * f1;
            acc[8+(e+2)/9] += c[(e+2)%9] * g2;
            acc[8+(e+3)/9] += c[(e+3)%9] * f3;
        }
    }

    // feats: fg block then bg block, contiguous 16 floats per pixel -> p*16
    float4* o = (float4*)(out + (size_t)p * 16);
    o[0] = make_float4(acc[0],  acc[1],  acc[2],  acc[3]);
    o[1] = make_float4(acc[4],  acc[5],  acc[6],  acc[7]);
    o[2] = make_float4(acc[8],  acc[9],  acc[10], acc[11]);
    o[3] = make_float4(acc[12], acc[13], acc[14], acc[15]);
    // masks: after both feat blocks
    out[(size_t)2 * HW * 16 + p] = (m1 || m2) ? 1.0f : 0.0f;
}

extern "C" void kernel_launch(void* const* d_in, const int* in_sizes, int n_in,
                              void* d_out, int out_size, void* d_ws, size_t ws_size,
                              hipStream_t stream)
{
    const float* features = (const float*)d_in[0];
    const float* dists    = (const float*)d_in[1];
    const float* bary     = (const float*)d_in[2];
    const float* rd       = (const float*)d_in[3];
    const int*   faces    = (const int*)d_in[4];
    const int*   f1idx    = (const int*)d_in[5];
    const int*   p2f      = (const int*)d_in[6];
    float* out = (float*)d_out;

    int HW = in_sizes[1] / 2;   // frag1_dists has 2*H*W elements
    int N  = 2 * HW;

    const int block = 256;
    const int grid  = (N + block - 1) / block;
    hipLaunchKernelGGL(net_tex_kernel, dim3(grid), dim3(block), 0, stream,
                       features, dists, bary, rd, faces, f1idx, p2f, out, HW, N);
}

// Round 2
// 206.496 us; speedup vs baseline: 1.2503x; 1.2503x over previous
//
#include <hip/hip_runtime.h>

// NetAndTexture: fused feature-gather + barycentric blend + SH2 eval.
// 4 lanes per pixel-layer: lane0 = frag1 row, lanes1-3 = triangle vertex rows.
// out layout (floats): [HW*16 fg feats][HW*16 bg feats][HW fg mask][HW bg mask]

constexpr float SH_C0 = 0.28209479177387814f;
constexpr float SH_C1 = 0.4886025119029199f;
constexpr float C20 =  1.0925484305920792f;
constexpr float C21 = -1.0925484305920792f;
constexpr float C22 =  0.31539156525252005f;
constexpr float C23 = -1.0925484305920792f;
constexpr float C24 =  0.5462742152960396f;
constexpr float INV_R2 = 1.0f / (0.006f * 0.006f);

__global__ __launch_bounds__(256) void net_tex_kernel4(
    const float* __restrict__ features,
    const float* __restrict__ dists,
    const float* __restrict__ bary,
    const float* __restrict__ rd,
    const int*  __restrict__ faces,
    const int*  __restrict__ f1idx,
    const int*  __restrict__ p2f,
    float* __restrict__ out,
    int HW, int N)
{
    int q = blockIdx.x * blockDim.x + threadIdx.x;
    int p = q >> 2;          // pixel-layer, uniform across the 4-lane group
    int r = q & 3;           // role within group
    if (p >= N) return;

    int s  = (p >= HW) ? 1 : 0;
    int hw = p - s * HW;

    // dirs = flip(ray_dirs over H,W) -> rd[k*HW + (HW-1-hw)]
    float x = rd[HW   - 1 - hw];
    float y = rd[2*HW - 1 - hw];
    float z = rd[3*HW - 1 - hw];
    float xx = x*x, yy = y*y, zz = z*z;
    float c[9];
    c[0] = SH_C0;
    c[1] = -SH_C1 * y;
    c[2] =  SH_C1 * z;
    c[3] = -SH_C1 * x;
    c[4] = C20 * x * y;
    c[5] = C21 * y * z;
    c[6] = C22 * (2.0f*zz - xx - yy);
    c[7] = C23 * x * z;
    c[8] = C24 * (xx - yy);

    // Pick this lane's feature row + weight.
    int  idx;
    float w;
    bool valid;
    if (r == 0) {
        int i1 = f1idx[p];
        valid = (i1 >= 0);
        idx = valid ? i1 : 0;
        w = 1.0f - dists[p] * INV_R2;
    } else {
        int f2 = p2f[p];
        valid = (f2 >= 0);
        int fb = (valid ? f2 : 0) * 3;
        idx = faces[fb + (r - 1)];
        w = bary[(size_t)p * 3 + (r - 1)];
    }

    float d[8];
    #pragma unroll
    for (int j = 0; j < 8; j++) d[j] = 0.0f;

    if (valid) {
        const float4* row = (const float4*)(features + (size_t)idx * 72);
        #pragma unroll
        for (int ch = 0; ch < 18; ch++) {
            float4 v = row[ch];
            const int e = ch * 4;
            d[(e+0)/9] += c[(e+0)%9] * v.x;
            d[(e+1)/9] += c[(e+1)%9] * v.y;
            d[(e+2)/9] += c[(e+2)%9] * v.z;
            d[(e+3)/9] += c[(e+3)%9] * v.w;
        }
        #pragma unroll
        for (int j = 0; j < 8; j++) d[j] *= w;
    }

    // Reduce lanes 1..3 (bg color channels 8-15) within the 4-lane group.
    float sum[8];
    #pragma unroll
    for (int j = 0; j < 8; j++) {
        float t = (r == 0) ? 0.0f : d[j];
        t += __shfl_xor(t, 1, 64);
        t += __shfl_xor(t, 2, 64);
        sum[j] = t;
    }

    // m1||m2: lane0 holds m1, lanes1-3 hold m2 -> any valid in the nibble.
    unsigned long long bal = __ballot(valid);
    int lane = threadIdx.x & 63;
    bool any = ((bal >> (lane & ~3)) & 0xFULL) != 0;

    float4* o = (float4*)(out + (size_t)p * 16);
    if (r == 0) {
        o[0] = make_float4(d[0], d[1], d[2], d[3]);
        o[1] = make_float4(d[4], d[5], d[6], d[7]);
    } else if (r == 1) {
        o[2] = make_float4(sum[0], sum[1], sum[2], sum[3]);
        o[3] = make_float4(sum[4], sum[5], sum[6], sum[7]);
    } else if (r == 2) {
        out[(size_t)2 * HW * 16 + p] = any ? 1.0f : 0.0f;
    }
}

extern "C" void kernel_launch(void* const* d_in, const int* in_sizes, int n_in,
                              void* d_out, int out_size, void* d_ws, size_t ws_size,
                              hipStream_t stream)
{
    const float* features = (const float*)d_in[0];
    const float* dists    = (const float*)d_in[1];
    const float* bary     = (const float*)d_in[2];
    const float* rd       = (const float*)d_in[3];
    const int*   faces    = (const int*)d_in[4];
    const int*   f1idx    = (const int*)d_in[5];
    const int*   p2f      = (const int*)d_in[6];
    float* out = (float*)d_out;

    int HW = in_sizes[1] / 2;   // frag1_dists has 2*H*W elements
    int N  = 2 * HW;            // pixel-layers
    long long threads = (long long)N * 4;

    const int block = 256;
    const int grid  = (int)((threads + block - 1) / block);
    hipLaunchKernelGGL(net_tex_kernel4, dim3(grid), dim3(block), 0, stream,
                       features, dists, bary, rd, faces, f1idx, p2f, out, HW, N);
}

// Round 3
// 194.234 us; speedup vs baseline: 1.3293x; 1.0631x over previous
//
#include <hip/hip_runtime.h>

// NetAndTexture: fused feature-gather + barycentric blend + SH2 eval.
// 8 lanes per pixel-layer: r = role*2 + half.
//   role 0   = frag1 row   (weighted by 1 - d/R^2)  -> out channels 0-7
//   role 1-3 = triangle vertex rows (x barycentric)  -> out channels 8-15
//   half selects 36-float half of the 72-float row; 36%9==0 so both halves
//   share the same (k/9, k%9) channel/coeff pattern -> zero divergence.
// out layout (floats): [HW*16 fg feats][HW*16 bg feats][HW fg mask][HW bg mask]

constexpr float SH_C0 = 0.28209479177387814f;
constexpr float SH_C1 = 0.4886025119029199f;
constexpr float C20 =  1.0925484305920792f;
constexpr float C21 = -1.0925484305920792f;
constexpr float C22 =  0.31539156525252005f;
constexpr float C23 = -1.0925484305920792f;
constexpr float C24 =  0.5462742152960396f;
constexpr float INV_R2 = 1.0f / (0.006f * 0.006f);

__global__ __launch_bounds__(256) void net_tex_kernel8(
    const float* __restrict__ features,
    const float* __restrict__ dists,
    const float* __restrict__ bary,
    const float* __restrict__ rd,
    const int*  __restrict__ faces,
    const int*  __restrict__ f1idx,
    const int*  __restrict__ p2f,
    float* __restrict__ out,
    int HW, int N)
{
    int q = blockIdx.x * blockDim.x + threadIdx.x;
    int p = q >> 3;            // pixel-layer (uniform across 8-lane group)
    int r = q & 7;
    if (p >= N) return;
    int role = r >> 1;
    int half = r & 1;

    int s  = (p >= HW) ? 1 : 0;
    int hw = p - s * HW;

    // dirs = flip(ray_dirs over H,W) -> rd[k*HW + (HW-1-hw)]
    float x = rd[HW   - 1 - hw];
    float y = rd[2*HW - 1 - hw];
    float z = rd[3*HW - 1 - hw];
    float xx = x*x, yy = y*y, zz = z*z;
    float c[9];
    c[0] = SH_C0;
    c[1] = -SH_C1 * y;
    c[2] =  SH_C1 * z;
    c[3] = -SH_C1 * x;
    c[4] = C20 * x * y;
    c[5] = C21 * y * z;
    c[6] = C22 * (2.0f*zz - xx - yy);
    c[7] = C23 * x * z;
    c[8] = C24 * (xx - yy);

    // Pick this lane's feature row + weight.
    int   idx;
    float w;
    bool  valid;
    if (role == 0) {
        int i1 = f1idx[p];
        valid = (i1 >= 0);
        idx = valid ? i1 : 0;
        w = 1.0f - dists[p] * INV_R2;
    } else {
        int f2 = p2f[p];
        valid = (f2 >= 0);
        int fb = (valid ? f2 : 0) * 3;
        idx = faces[fb + (role - 1)];
        w = bary[(size_t)p * 3 + (role - 1)];
    }

    float d[4];
    #pragma unroll
    for (int j = 0; j < 4; j++) d[j] = 0.0f;

    if (valid) {
        const float4* row =
            (const float4*)(features + (size_t)idx * 72) + half * 9;
        #pragma unroll
        for (int ch = 0; ch < 9; ch++) {
            float4 v = row[ch];
            const int e = ch * 4;          // 36%9==0: same pattern both halves
            d[(e+0)/9] += c[(e+0)%9] * v.x;
            d[(e+1)/9] += c[(e+1)%9] * v.y;
            d[(e+2)/9] += c[(e+2)%9] * v.z;
            d[(e+3)/9] += c[(e+3)%9] * v.w;
        }
        #pragma unroll
        for (int j = 0; j < 4; j++) d[j] *= w;
    }

    // Sum the three vertex rows (roles 1-3) within same half: xor over bits 1,2
    // of r covers roles {0,1,2,3}; role0's contribution is zeroed.
    float sum[4];
    #pragma unroll
    for (int j = 0; j < 4; j++) {
        float t = (role == 0) ? 0.0f : d[j];
        t += __shfl_xor(t, 2, 64);
        t += __shfl_xor(t, 4, 64);
        sum[j] = t;
    }

    // final mask = m1 || m2 over the 8-lane group.
    unsigned long long bal = __ballot(valid);
    int lane = threadIdx.x & 63;
    bool any = ((bal >> (lane & ~7)) & 0xFFULL) != 0;

    float4* o = (float4*)(out + (size_t)p * 16);
    if (r == 0) {
        o[0] = make_float4(d[0], d[1], d[2], d[3]);     // fg ch 0-3
    } else if (r == 1) {
        o[1] = make_float4(d[0], d[1], d[2], d[3]);     // fg ch 4-7
    } else if (r == 2) {
        o[2] = make_float4(sum[0], sum[1], sum[2], sum[3]); // bg ch 8-11
    } else if (r == 3) {
        o[3] = make_float4(sum[0], sum[1], sum[2], sum[3]); // bg ch 12-15
    } else if (r == 4) {
        out[(size_t)2 * HW * 16 + p] = any ? 1.0f : 0.0f;
    }
}

extern "C" void kernel_launch(void* const* d_in, const int* in_sizes, int n_in,
                              void* d_out, int out_size, void* d_ws, size_t ws_size,
                              hipStream_t stream)
{
    const float* features = (const float*)d_in[0];
    const float* dists    = (const float*)d_in[1];
    const float* bary     = (const float*)d_in[2];
    const float* rd       = (const float*)d_in[3];
    const int*   faces    = (const int*)d_in[4];
    const int*   f1idx    = (const int*)d_in[5];
    const int*   p2f      = (const int*)d_in[6];
    float* out = (float*)d_out;

    int HW = in_sizes[1] / 2;   // frag1_dists has 2*H*W elements
    int N  = 2 * HW;            // pixel-layers
    long long threads = (long long)N * 8;

    const int block = 256;
    const int grid  = (int)((threads + block - 1) / block);
    hipLaunchKernelGGL(net_tex_kernel8, dim3(grid), dim3(block), 0, stream,
                       features, dists, bary, rd, faces, f1idx, p2f, out, HW, N);
}